// Round 2
// baseline (606.791 us; speedup 1.0000x reference)
//
#include <hip/hip_runtime.h>

typedef float f32x4 __attribute__((ext_vector_type(4)));
typedef short bf16x8 __attribute__((ext_vector_type(8)));
typedef unsigned short u16;

#define NEG_INF (-1e30f)

__device__ __forceinline__ u16 f2bf(float f) {
    unsigned u = __builtin_bit_cast(unsigned, f);
    unsigned r = u + 0x7FFFu + ((u >> 16) & 1u);  // RNE
    return (u16)(r >> 16);
}
// 2x f32 -> packed bf16 in one VALU op (RNE, identical to f2bf for normal values).
__device__ __forceinline__ unsigned pk2(float a, float b) {
    unsigned r;
    asm("v_cvt_pk_bf16_f32 %0, %1, %2" : "=v"(r) : "v"(a), "v"(b));
    return r;
}

__device__ __forceinline__ float wave_max(float v) {
    #pragma unroll
    for (int o = 32; o > 0; o >>= 1) v = fmaxf(v, __shfl_xor(v, o, 64));
    return v;
}
__device__ __forceinline__ float wave_sum(float v) {
    #pragma unroll
    for (int o = 32; o > 0; o >>= 1) v += __shfl_xor(v, o, 64);
    return v;
}
__device__ __forceinline__ void wave_argmax(float& v, int& i) {
    #pragma unroll
    for (int o = 32; o > 0; o >>= 1) {
        float ov = __shfl_xor(v, o, 64);
        int oi = __shfl_xor(i, o, 64);
        if (ov > v || (ov == v && oi < i)) { v = ov; i = oi; }
    }
}

// ---------------- staging ----------------
// Async global->LDS 16B. LDS dest is wave-uniform base + lane*16 by construction:
// e = r*2048 + tid*8 -> per-wave byte base r*4096 + wave*1024, lane offset lane*16.
__device__ __forceinline__ void g2l16(const void* g, void* l) {
    __builtin_amdgcn_global_load_lds((__attribute__((address_space(1))) void*)g,
                                     (__attribute__((address_space(3))) void*)l,
                                     16, 0, 0);
}

// Stage ROWSx64 bf16 tile (row-major, leading dim ld) into linear LDS [ROWS][64].
template<int NROUND>
__device__ __forceinline__ void stage_bf16(const u16* __restrict__ src, int ld,
                                           u16* dst, int tid) {
    #pragma unroll
    for (int r = 0; r < NROUND; ++r) {
        int e = r * 2048 + tid * 8;
        int row = e >> 6, col = e & 63;
        g2l16(src + (size_t)row * ld + col, dst + e);
    }
}

// Stage ROWSx64 fp32 tile -> bf16 LDS (cvt_pk RNE in flight), via registers.
template<int NROUND>
__device__ __forceinline__ void stage_f32(const float* __restrict__ src, int ld,
                                          u16* dst, int tid) {
    #pragma unroll
    for (int r = 0; r < NROUND; ++r) {
        int e = r * 2048 + tid * 8;
        int row = e >> 6, col = e & 63;
        const float* s = src + (size_t)row * ld + col;
        float4 a = *reinterpret_cast<const float4*>(s);
        float4 b = *reinterpret_cast<const float4*>(s + 4);
        uint4 pk;
        pk.x = pk2(a.x, a.y); pk.y = pk2(a.z, a.w);
        pk.z = pk2(b.x, b.y); pk.w = pk2(b.z, b.w);
        *reinterpret_cast<uint4*>(dst + e) = pk;
    }
}

// A/B-frag for mfma_f32_16x16x32_bf16 from linear LDS [*][64]:
// lane holds [m|n = lane&15][k = ks*32 + (lane>>4)*8 .. +7]
__device__ __forceinline__ bf16x8 frag(const u16* lds, int row0, int ks, int lane) {
    return *reinterpret_cast<const bf16x8*>(
        lds + (row0 + (lane & 15)) * 64 + ks * 32 + (lane >> 4) * 8);
}

// ---------------- router GEMM: R[4096,256] = x @ [rxw;ryw]^T, fused fp32->bf16 ----------------
__global__ __launch_bounds__(256, 2) void gemm_router(
    const float* __restrict__ X, const float* __restrict__ RX, const float* __restrict__ RY,
    float* __restrict__ R) {
    __shared__ u16 As[8192];   // 128x64
    __shared__ u16 Bs[4096];   // 64x64
    int tid = threadIdx.x, lane = tid & 63, wave = tid >> 6;
    int rowBase = blockIdx.y * 128, colBase = blockIdx.x * 64;
    const float* Bp = (blockIdx.x < 2) ? RX + (size_t)colBase * 1024
                                       : RY + (size_t)(colBase - 128) * 1024;
    int wm = (wave >> 1) * 64, wn = (wave & 1) * 32;
    f32x4 acc[4][2] = {};
    for (int k0 = 0; k0 < 1024; k0 += 64) {
        stage_f32<4>(X + (size_t)rowBase * 1024 + k0, 1024, As, tid);
        stage_f32<2>(Bp + k0, 1024, Bs, tid);
        __syncthreads();
        #pragma unroll
        for (int ks = 0; ks < 2; ++ks) {
            bf16x8 af[4], bfr[2];
            #pragma unroll
            for (int i = 0; i < 4; ++i) af[i] = frag(As, wm + i * 16, ks, lane);
            #pragma unroll
            for (int j = 0; j < 2; ++j) bfr[j] = frag(Bs, wn + j * 16, ks, lane);
            #pragma unroll
            for (int i = 0; i < 4; ++i)
                #pragma unroll
                for (int j = 0; j < 2; ++j)
                    acc[i][j] = __builtin_amdgcn_mfma_f32_16x16x32_bf16(af[i], bfr[j], acc[i][j], 0, 0, 0);
        }
        __syncthreads();
    }
    int rq = (lane >> 4) * 4, cq = lane & 15;
    #pragma unroll
    for (int i = 0; i < 4; ++i)
        #pragma unroll
        for (int j = 0; j < 2; ++j) {
            int col = colBase + wn + j * 16 + cq;
            #pragma unroll
            for (int r = 0; r < 4; ++r) {
                int row = rowBase + wm + i * 16 + rq + r;
                R[(size_t)row * 256 + col] = acc[i][j][r];
            }
        }
}

// ---------------- fused gate/up GEMM + expert combine (blockIdx-partitioned) ----------------
// b%3==0 -> gateup block g=b/3: H2[gy*128.., gx*64..] = silu(x Gt)*(x Ut), bf16 out.
// else   -> expert block n=b-b/3-1: experts term for token n -> Out (fp32).
__global__ __launch_bounds__(256, 2) void gateup_expert(
    const float* __restrict__ X, const float* __restrict__ GW, const float* __restrict__ UW,
    u16* __restrict__ H2,
    const float* __restrict__ UE, const float* __restrict__ DE,
    const int* __restrict__ idxs, const float* __restrict__ wts, float* __restrict__ Out) {
    __shared__ __align__(16) char smem[32768];
    int b = blockIdx.x, tid = threadIdx.x;
    int lane = tid & 63, wave = tid >> 6;

    if (b % 3 == 0) {
        // ---- gateup ----
        int g = b / 3;
        int rowBase = (g >> 6) * 128, colBase = (g & 63) * 64;
        u16* As = (u16*)smem;            // 16KB: 128x64
        u16* Gs = (u16*)(smem + 16384);  //  8KB:  64x64
        u16* Us = (u16*)(smem + 24576);  //  8KB:  64x64
        int wm = (wave >> 1) * 64, wn = (wave & 1) * 32;
        f32x4 ag[4][2] = {}, au[4][2] = {};
        for (int k0 = 0; k0 < 1024; k0 += 64) {
            stage_f32<4>(X + (size_t)rowBase * 1024 + k0, 1024, As, tid);
            stage_f32<2>(GW + (size_t)colBase * 1024 + k0, 1024, Gs, tid);
            stage_f32<2>(UW + (size_t)colBase * 1024 + k0, 1024, Us, tid);
            __syncthreads();
            #pragma unroll
            for (int ks = 0; ks < 2; ++ks) {
                bf16x8 af[4], gf[2], uf[2];
                #pragma unroll
                for (int i = 0; i < 4; ++i) af[i] = frag(As, wm + i * 16, ks, lane);
                #pragma unroll
                for (int j = 0; j < 2; ++j) { gf[j] = frag(Gs, wn + j * 16, ks, lane);
                                              uf[j] = frag(Us, wn + j * 16, ks, lane); }
                #pragma unroll
                for (int i = 0; i < 4; ++i)
                    #pragma unroll
                    for (int j = 0; j < 2; ++j) {
                        ag[i][j] = __builtin_amdgcn_mfma_f32_16x16x32_bf16(af[i], gf[j], ag[i][j], 0, 0, 0);
                        au[i][j] = __builtin_amdgcn_mfma_f32_16x16x32_bf16(af[i], uf[j], au[i][j], 0, 0, 0);
                    }
            }
            __syncthreads();
        }
        int rq = (lane >> 4) * 4, cq = lane & 15;
        #pragma unroll
        for (int i = 0; i < 4; ++i)
            #pragma unroll
            for (int j = 0; j < 2; ++j) {
                int col = colBase + wn + j * 16 + cq;
                #pragma unroll
                for (int r = 0; r < 4; ++r) {
                    int row = rowBase + wm + i * 16 + rq + r;
                    float gv = ag[i][j][r], uv = au[i][j][r];
                    float h = (gv / (1.f + __expf(-gv))) * uv;   // silu(g)*u
                    H2[(size_t)row * 4096 + col] = f2bf(h);
                }
            }
    } else {
        // ---- expert combine ----
        int n = b - b / 3 - 1;
        float* xs  = (float*)smem;           // 4KB
        float* ews = (float*)(smem + 4096);
        int*  sidx = (int*)(smem + 4160);
        float* swt = (float*)(smem + 4224);
        if (tid < 16) {
            sidx[tid] = min(max(idxs[n * 16 + tid], 0), 16383);  // clamp: no wild gathers
            swt[tid] = wts[n * 16 + tid];
        }
        {
            float4 v = reinterpret_cast<const float4*>(X + (size_t)n * 1024)[tid];
            *reinterpret_cast<float4*>(xs + tid * 4) = v;
        }
        __syncthreads();
        #pragma unroll
        for (int q = 0; q < 4; ++q) {
            int e = wave * 4 + q;
            const float* row = UE + (size_t)sidx[e] * 1024;
            float acc = 0.f;
            #pragma unroll
            for (int c = 0; c < 4; ++c) {
                int h = c * 256 + lane * 4;
                float4 a = *reinterpret_cast<const float4*>(row + h);
                float4 xv = *reinterpret_cast<const float4*>(xs + h);
                acc += a.x * xv.x + a.y * xv.y + a.z * xv.z + a.w * xv.w;
            }
            acc = wave_sum(acc);
            if (lane == 0) {
                float s = acc / (1.f + __expf(-acc));   // silu
                ews[e] = s * swt[e];
            }
        }
        __syncthreads();
        float4 a = make_float4(0.f, 0.f, 0.f, 0.f);
        int h = tid * 4;
        #pragma unroll
        for (int e = 0; e < 16; ++e) {
            const float* row = DE + (size_t)sidx[e] * 1024;
            float4 v = *reinterpret_cast<const float4*>(row + h);
            float w = ews[e];
            a.x += w * v.x; a.y += w * v.y;
            a.z += w * v.z; a.w += w * v.w;
        }
        reinterpret_cast<float4*>(Out + (size_t)n * 1024)[tid] = a;
    }
}

// ---------------- down GEMM + experts add: Out += H2(bf16) @ dw^T, K=4096 ----------------
// 1-D grid of 512; XCD-aware decode: XCD k owns row-panels by = k*4..k*4+3 (4MB A-panel
// L2-resident per XCD; dw K-slices reused 4x within XCD).
__global__ __launch_bounds__(256, 2) void gemm_down_add(
    const u16* __restrict__ H2, const float* __restrict__ DW, float* __restrict__ Out) {
    __shared__ u16 As[8192];   // 128x64
    __shared__ u16 Bs[4096];   // 64x64
    int b = blockIdx.x, tid = threadIdx.x;
    int xcd = b & 7, i = b >> 3;
    int by = xcd * 4 + (i >> 4), bx = i & 15;
    int lane = tid & 63, wave = tid >> 6;
    int rowBase = by * 128, colBase = bx * 64;
    int wm = (wave >> 1) * 64, wn = (wave & 1) * 32;
    f32x4 acc[4][2] = {};
    for (int k0 = 0; k0 < 4096; k0 += 64) {
        stage_bf16<4>(H2 + (size_t)rowBase * 4096 + k0, 4096, As, tid);
        stage_f32<2>(DW + (size_t)colBase * 4096 + k0, 4096, Bs, tid);
        __syncthreads();
        #pragma unroll
        for (int ks = 0; ks < 2; ++ks) {
            bf16x8 af[4], bfr[2];
            #pragma unroll
            for (int i2 = 0; i2 < 4; ++i2) af[i2] = frag(As, wm + i2 * 16, ks, lane);
            #pragma unroll
            for (int j = 0; j < 2; ++j) bfr[j] = frag(Bs, wn + j * 16, ks, lane);
            #pragma unroll
            for (int i2 = 0; i2 < 4; ++i2)
                #pragma unroll
                for (int j = 0; j < 2; ++j)
                    acc[i2][j] = __builtin_amdgcn_mfma_f32_16x16x32_bf16(af[i2], bfr[j], acc[i2][j], 0, 0, 0);
        }
        __syncthreads();
    }
    int rq = (lane >> 4) * 4, cq = lane & 15;
    #pragma unroll
    for (int i2 = 0; i2 < 4; ++i2)
        #pragma unroll
        for (int j = 0; j < 2; ++j) {
            int col = colBase + wn + j * 16 + cq;
            #pragma unroll
            for (int r = 0; r < 4; ++r) {
                int row = rowBase + wm + i2 * 16 + rq + r;
                size_t o = (size_t)row * 1024 + col;
                Out[o] = acc[i2][j][r] + Out[o];   // add experts term (same-thread RMW)
            }
        }
}

// ---------------- router stats / topk (proven) ----------------
__global__ void bn_stats(const float* __restrict__ R, float* __restrict__ stats) {
    int c = threadIdx.x;
    int r0 = blockIdx.x * 64;
    float s = 0.f, s2 = 0.f;
    for (int r = r0; r < r0 + 64; ++r) {
        float v = R[(size_t)r * 256 + c];
        s += v; s2 += v * v;
    }
    atomicAdd(&stats[c], s);
    atomicAdd(&stats[256 + c], s2);
}

__global__ __launch_bounds__(64) void router_topk(
    const float* __restrict__ R, const float* __restrict__ stats,
    int* __restrict__ idx_out, float* __restrict__ wt_out) {
    int n = blockIdx.x, lane = threadIdx.x;
    const float invN = 1.0f / 4096.0f;
    float z[4];
    #pragma unroll
    for (int p = 0; p < 4; ++p) {
        int c = p * 64 + lane;
        float mean = stats[c] * invN;
        float var = fmaxf(stats[256 + c] * invN - mean * mean, 0.f);  // biased var
        float v = R[(size_t)n * 256 + c];
        z[p] = (v - mean) * rsqrtf(var + 1e-5f);
    }
    float mx = wave_max(fmaxf(z[0], z[1]));
    float sx = __logf(wave_sum(__expf(z[0] - mx) + __expf(z[1] - mx)));
    float lx0 = z[0] - mx - sx, lx1 = z[1] - mx - sx;
    float my = wave_max(fmaxf(z[2], z[3]));
    float sy = __logf(wave_sum(__expf(z[2] - my) + __expf(z[3] - my)));
    float ly0 = z[2] - my - sy, ly1 = z[3] - my - sy;

    __shared__ float tx[16], ty[16];
    __shared__ int txc[16], tyc[16];
    float v0 = lx0, v1 = lx1;
    for (int t = 0; t < 16; ++t) {
        float bv; int bc;
        if (v1 > v0) { bv = v1; bc = lane + 64; } else { bv = v0; bc = lane; }
        wave_argmax(bv, bc);
        if (lane == 0) { tx[t] = bv; txc[t] = bc; }
        if (bc == lane) v0 = NEG_INF;
        else if (bc == lane + 64) v1 = NEG_INF;
    }
    v0 = ly0; v1 = ly1;
    for (int t = 0; t < 16; ++t) {
        float bv; int bc;
        if (v1 > v0) { bv = v1; bc = lane + 64; } else { bv = v0; bc = lane; }
        wave_argmax(bv, bc);
        if (lane == 0) { ty[t] = bv; tyc[t] = bc; }
        if (bc == lane) v0 = NEG_INF;
        else if (bc == lane + 64) v1 = NEG_INF;
    }
    __syncthreads();
    float cv[4]; int ci[4];
    #pragma unroll
    for (int p = 0; p < 4; ++p) {
        int pid = p * 64 + lane;
        cv[p] = tx[pid >> 4] + ty[pid & 15];
        ci[p] = pid;
    }
    for (int t = 0; t < 16; ++t) {
        float bv = cv[0]; int bc = ci[0];
        #pragma unroll
        for (int p = 1; p < 4; ++p)
            if (cv[p] > bv) { bv = cv[p]; bc = ci[p]; }
        wave_argmax(bv, bc);
        if (lane == 0) {
            idx_out[n * 16 + t] = txc[bc >> 4] * 128 + tyc[bc & 15];
            wt_out[n * 16 + t] = __expf(bv);
        }
        #pragma unroll
        for (int p = 0; p < 4; ++p)
            if (ci[p] == bc) cv[p] = NEG_INF;
    }
}

// ---------------- host ----------------
// Workspace: stats 16KB | idx 256KB | wt 256KB | union32 { R 4MB (router) -> H2 32MB (dense) }
// Total 34.1MB < proven 38.3MB floor. No weight staging buffer: all fp32->bf16 conversion is
// fused into LDS staging (v_cvt_pk_bf16_f32, RNE). 6 launches total.
extern "C" void kernel_launch(void* const* d_in, const int* in_sizes, int n_in,
                              void* d_out, int out_size, void* d_ws, size_t ws_size,
                              hipStream_t stream) {
    const float* x   = (const float*)d_in[0];   // [4096,1024]
    const float* gw  = (const float*)d_in[1];   // [4096,1024]
    const float* uw  = (const float*)d_in[2];   // [4096,1024]
    const float* dw  = (const float*)d_in[3];   // [1024,4096]
    const float* rxw = (const float*)d_in[4];   // [128,1024]
    const float* ryw = (const float*)d_in[5];   // [128,1024]
    const float* ue  = (const float*)d_in[6];   // [16384,1024]
    const float* de  = (const float*)d_in[7];   // [16384,1024]
    float* out = (float*)d_out;                 // [4096,1024] fp32

    char* p = (char*)d_ws;
    float* stats = (float*)p; p += 16384;
    int*   idxb  = (int*)p;   p += 262144;
    float* wtb   = (float*)p; p += 262144;
    float* R     = (float*)p;                   // [4096,256] fp32, dead after router_topk
    u16*   H2    = (u16*)p;                     // aliases R: [4096,4096] bf16 (dense phase)

    hipMemsetAsync(stats, 0, 512 * sizeof(float), stream);
    gemm_router<<<dim3(4, 32), 256, 0, stream>>>(x, rxw, ryw, R);
    bn_stats<<<64, 256, 0, stream>>>(R, stats);
    router_topk<<<4096, 64, 0, stream>>>(R, stats, idxb, wtb);
    // fused: 2048 gateup blocks + 4096 expert blocks, interleaved 1:2 for co-scheduling
    gateup_expert<<<6144, 256, 0, stream>>>(x, gw, uw, H2, ue, de, idxb, wtb, out);
    gemm_down_add<<<512, 256, 0, stream>>>(H2, dw, out);
}

// Round 3
// 546.031 us; speedup vs baseline: 1.1113x; 1.1113x over previous
//
#include <hip/hip_runtime.h>

typedef float f32x4 __attribute__((ext_vector_type(4)));
typedef short bf16x8 __attribute__((ext_vector_type(8)));
typedef unsigned short u16;

#define NEG_INF (-1e30f)

__device__ __forceinline__ u16 f2bf(float f) {
    unsigned u = __builtin_bit_cast(unsigned, f);
    unsigned r = u + 0x7FFFu + ((u >> 16) & 1u);  // RNE
    return (u16)(r >> 16);
}
// 2x f32 -> packed bf16 in one VALU op (RNE, identical to f2bf; validated round 2).
__device__ __forceinline__ unsigned pk2(float a, float b) {
    unsigned r;
    asm("v_cvt_pk_bf16_f32 %0, %1, %2" : "=v"(r) : "v"(a), "v"(b));
    return r;
}

__device__ __forceinline__ float wave_max(float v) {
    #pragma unroll
    for (int o = 32; o > 0; o >>= 1) v = fmaxf(v, __shfl_xor(v, o, 64));
    return v;
}
__device__ __forceinline__ float wave_sum(float v) {
    #pragma unroll
    for (int o = 32; o > 0; o >>= 1) v += __shfl_xor(v, o, 64);
    return v;
}
__device__ __forceinline__ void wave_argmax(float& v, int& i) {
    #pragma unroll
    for (int o = 32; o > 0; o >>= 1) {
        float ov = __shfl_xor(v, o, 64);
        int oi = __shfl_xor(i, o, 64);
        if (ov > v || (ov == v && oi < i)) { v = ov; i = oi; }
    }
}

// ---------------- staging ----------------
// Async global->LDS 16B. LDS dest must be wave-uniform base + lane*16 (holds by
// construction in all stage_* below: elem offset = const + wave*512 + lane*8).
__device__ __forceinline__ void g2l16(const void* g, void* l) {
    __builtin_amdgcn_global_load_lds((__attribute__((address_space(1))) void*)g,
                                     (__attribute__((address_space(3))) void*)l,
                                     16, 0, 0);
}

// ---- BK=64 tiles: LDS [ROWS][64] ----
template<int NROUND>   // NROUND = ROWS/32
__device__ __forceinline__ void stage_bf16(const u16* __restrict__ src, int ld,
                                           u16* dst, int tid) {
    #pragma unroll
    for (int r = 0; r < NROUND; ++r) {
        int e = r * 2048 + tid * 8;
        int row = e >> 6, col = e & 63;
        g2l16(src + (size_t)row * ld + col, dst + e);
    }
}
template<int NROUND>   // NROUND = ROWS/32
__device__ __forceinline__ void stage_f32(const float* __restrict__ src, int ld,
                                          u16* dst, int tid) {
    #pragma unroll
    for (int r = 0; r < NROUND; ++r) {
        int e = r * 2048 + tid * 8;
        int row = e >> 6, col = e & 63;
        const float* s = src + (size_t)row * ld + col;
        float4 a = *reinterpret_cast<const float4*>(s);
        float4 b = *reinterpret_cast<const float4*>(s + 4);
        uint4 pk;
        pk.x = pk2(a.x, a.y); pk.y = pk2(a.z, a.w);
        pk.z = pk2(b.x, b.y); pk.w = pk2(b.z, b.w);
        *reinterpret_cast<uint4*>(dst + e) = pk;
    }
}
// lane holds [m|n = lane&15][k = ks*32 + (lane>>4)*8 .. +7]
__device__ __forceinline__ bf16x8 frag(const u16* lds, int row0, int ks, int lane) {
    return *reinterpret_cast<const bf16x8*>(
        lds + (row0 + (lane & 15)) * 64 + ks * 32 + (lane >> 4) * 8);
}

// ---- BK=32 tiles: LDS [ROWS][32] ----
template<int NROUND>   // NROUND = ROWS/64
__device__ __forceinline__ void stage32_bf16(const u16* __restrict__ src, int ld,
                                             u16* dst, int tid) {
    #pragma unroll
    for (int r = 0; r < NROUND; ++r) {
        int e = r * 2048 + tid * 8;
        int row = e >> 5, col = e & 31;
        g2l16(src + (size_t)row * ld + col, dst + e);
    }
}
template<int NROUND>   // NROUND = ROWS/32
__device__ __forceinline__ void stage32_f32(const float* __restrict__ src, int ld,
                                            u16* dst, int tid) {
    #pragma unroll
    for (int r = 0; r < NROUND; ++r) {
        int e = r * 1024 + tid * 4;
        int row = e >> 5, col = e & 31;
        float4 v = *reinterpret_cast<const float4*>(src + (size_t)row * ld + col);
        uint2 pk;
        pk.x = pk2(v.x, v.y); pk.y = pk2(v.z, v.w);
        *reinterpret_cast<uint2*>(dst + e) = pk;
    }
}
__device__ __forceinline__ bf16x8 frag32(const u16* lds, int row0, int lane) {
    return *reinterpret_cast<const bf16x8*>(
        lds + (row0 + (lane & 15)) * 32 + (lane >> 4) * 8);
}

// ---------------- x -> bf16 (one-time; x is contiguous [4096][1024]) ----------------
__global__ void conv_x(const float* __restrict__ s, u16* __restrict__ d) {
    size_t i = (size_t)blockIdx.x * 256 + threadIdx.x;   // float4 index
    float4 v = *reinterpret_cast<const float4*>(s + i * 4);
    uint2 pk;
    pk.x = pk2(v.x, v.y); pk.y = pk2(v.z, v.w);
    *reinterpret_cast<uint2*>(d + i * 4) = pk;
}

// ---------------- router GEMM: R[4096,256] = x @ [rxw;ryw]^T (proven) ----------------
__global__ __launch_bounds__(256, 2) void gemm_router(
    const float* __restrict__ X, const float* __restrict__ RX, const float* __restrict__ RY,
    float* __restrict__ R) {
    __shared__ u16 As[8192];   // 128x64
    __shared__ u16 Bs[4096];   // 64x64
    int tid = threadIdx.x, lane = tid & 63, wave = tid >> 6;
    int rowBase = blockIdx.y * 128, colBase = blockIdx.x * 64;
    const float* Bp = (blockIdx.x < 2) ? RX + (size_t)colBase * 1024
                                       : RY + (size_t)(colBase - 128) * 1024;
    int wm = (wave >> 1) * 64, wn = (wave & 1) * 32;
    f32x4 acc[4][2] = {};
    for (int k0 = 0; k0 < 1024; k0 += 64) {
        stage_f32<4>(X + (size_t)rowBase * 1024 + k0, 1024, As, tid);
        stage_f32<2>(Bp + k0, 1024, Bs, tid);
        __syncthreads();
        #pragma unroll
        for (int ks = 0; ks < 2; ++ks) {
            bf16x8 af[4], bfr[2];
            #pragma unroll
            for (int i = 0; i < 4; ++i) af[i] = frag(As, wm + i * 16, ks, lane);
            #pragma unroll
            for (int j = 0; j < 2; ++j) bfr[j] = frag(Bs, wn + j * 16, ks, lane);
            #pragma unroll
            for (int i = 0; i < 4; ++i)
                #pragma unroll
                for (int j = 0; j < 2; ++j)
                    acc[i][j] = __builtin_amdgcn_mfma_f32_16x16x32_bf16(af[i], bfr[j], acc[i][j], 0, 0, 0);
        }
        __syncthreads();
    }
    int rq = (lane >> 4) * 4, cq = lane & 15;
    #pragma unroll
    for (int i = 0; i < 4; ++i)
        #pragma unroll
        for (int j = 0; j < 2; ++j) {
            int col = colBase + wn + j * 16 + cq;
            #pragma unroll
            for (int r = 0; r < 4; ++r) {
                int row = rowBase + wm + i * 16 + rq + r;
                R[(size_t)row * 256 + col] = acc[i][j][r];
            }
        }
}

// ---------------- gateup: m97 shape. 128x128 tile, BK=32, 24KB LDS, 4 waves 2x2 ----------
// H2[128*by.., 128*bx..] = silu(x Gt) * (x Ut), bf16 out. K=1024.
// XCD decode: XCD k owns row-panels k*4..k*4+3 (1MB xb panel L2-resident per XCD).
template<bool ABF>
__global__ __launch_bounds__(256, 2) void gemm_gateup(
    const float* __restrict__ Xf, const u16* __restrict__ Xb,
    const float* __restrict__ GW, const float* __restrict__ UW,
    u16* __restrict__ H2) {
    __shared__ u16 As[4096];   // 128x32
    __shared__ u16 Gs[4096];   // 128x32
    __shared__ u16 Us[4096];   // 128x32
    int tid = threadIdx.x, lane = tid & 63, wave = tid >> 6;
    int b = blockIdx.x;
    int xcd = b & 7, ii = b >> 3;                 // ii in 0..127
    int by = xcd * 4 + (ii >> 5), bx = ii & 31;
    int rowBase = by * 128, colBase = bx * 128;
    int wm = (wave >> 1) * 64, wn = (wave & 1) * 64;
    f32x4 accg[4][4] = {}, accu[4][4] = {};
    for (int k0 = 0; k0 < 1024; k0 += 32) {
        if constexpr (ABF) stage32_bf16<2>(Xb + (size_t)rowBase * 1024 + k0, 1024, As, tid);
        else               stage32_f32<4>(Xf + (size_t)rowBase * 1024 + k0, 1024, As, tid);
        stage32_f32<4>(GW + (size_t)colBase * 1024 + k0, 1024, Gs, tid);
        stage32_f32<4>(UW + (size_t)colBase * 1024 + k0, 1024, Us, tid);
        __syncthreads();
        bf16x8 gf[4], uf[4];
        #pragma unroll
        for (int j = 0; j < 4; ++j) { gf[j] = frag32(Gs, wn + j * 16, lane);
                                      uf[j] = frag32(Us, wn + j * 16, lane); }
        #pragma unroll
        for (int i = 0; i < 4; ++i) {
            bf16x8 af = frag32(As, wm + i * 16, lane);
            #pragma unroll
            for (int j = 0; j < 4; ++j) {
                accg[i][j] = __builtin_amdgcn_mfma_f32_16x16x32_bf16(af, gf[j], accg[i][j], 0, 0, 0);
                accu[i][j] = __builtin_amdgcn_mfma_f32_16x16x32_bf16(af, uf[j], accu[i][j], 0, 0, 0);
            }
        }
        __syncthreads();
    }
    int rq = (lane >> 4) * 4, cq = lane & 15;
    #pragma unroll
    for (int i = 0; i < 4; ++i)
        #pragma unroll
        for (int j = 0; j < 4; ++j) {
            int col = colBase + wn + j * 16 + cq;
            #pragma unroll
            for (int r = 0; r < 4; ++r) {
                int row = rowBase + wm + i * 16 + rq + r;
                float gv = accg[i][j][r], uv = accu[i][j][r];
                float h = (gv / (1.f + __expf(-gv))) * uv;   // silu(g)*u
                H2[(size_t)row * 4096 + col] = f2bf(h);
            }
        }
}

// ---------------- down GEMM + experts add: Out += H2(bf16) @ dw^T, K=4096 (proven) -------
__global__ __launch_bounds__(256, 2) void gemm_down_add(
    const u16* __restrict__ H2, const float* __restrict__ DW, float* __restrict__ Out) {
    __shared__ u16 As[8192];   // 128x64
    __shared__ u16 Bs[4096];   // 64x64
    int b = blockIdx.x, tid = threadIdx.x;
    int xcd = b & 7, ii = b >> 3;
    int by = xcd * 4 + (ii >> 4), bx = ii & 15;
    int lane = tid & 63, wave = tid >> 6;
    int rowBase = by * 128, colBase = bx * 64;
    int wm = (wave >> 1) * 64, wn = (wave & 1) * 32;
    f32x4 acc[4][2] = {};
    for (int k0 = 0; k0 < 4096; k0 += 64) {
        stage_bf16<4>(H2 + (size_t)rowBase * 4096 + k0, 4096, As, tid);
        stage_f32<2>(DW + (size_t)colBase * 4096 + k0, 4096, Bs, tid);
        __syncthreads();
        #pragma unroll
        for (int ks = 0; ks < 2; ++ks) {
            bf16x8 af[4], bfr[2];
            #pragma unroll
            for (int i2 = 0; i2 < 4; ++i2) af[i2] = frag(As, wm + i2 * 16, ks, lane);
            #pragma unroll
            for (int j = 0; j < 2; ++j) bfr[j] = frag(Bs, wn + j * 16, ks, lane);
            #pragma unroll
            for (int i2 = 0; i2 < 4; ++i2)
                #pragma unroll
                for (int j = 0; j < 2; ++j)
                    acc[i2][j] = __builtin_amdgcn_mfma_f32_16x16x32_bf16(af[i2], bfr[j], acc[i2][j], 0, 0, 0);
        }
        __syncthreads();
    }
    int rq = (lane >> 4) * 4, cq = lane & 15;
    #pragma unroll
    for (int i2 = 0; i2 < 4; ++i2)
        #pragma unroll
        for (int j = 0; j < 2; ++j) {
            int col = colBase + wn + j * 16 + cq;
            #pragma unroll
            for (int r = 0; r < 4; ++r) {
                int row = rowBase + wm + i2 * 16 + rq + r;
                size_t o = (size_t)row * 1024 + col;
                Out[o] = acc[i2][j][r] + Out[o];   // add experts term (same-thread RMW)
            }
        }
}

// ---------------- expert combine (round-1 exact: 4.6KB LDS, high occupancy) -------------
__global__ __launch_bounds__(256) void expert_store(
    const float* __restrict__ X, const float* __restrict__ UE, const float* __restrict__ DE,
    const int* __restrict__ idxs, const float* __restrict__ wts, float* __restrict__ Out) {
    int n = blockIdx.x, tid = threadIdx.x;
    int lane = tid & 63, wave = tid >> 6;
    __shared__ float xs[1024];
    __shared__ float ews[16];
    __shared__ int sidx[16];
    __shared__ float swt[16];
    if (tid < 16) {
        sidx[tid] = min(max(idxs[n * 16 + tid], 0), 16383);  // clamp: no wild gathers
        swt[tid] = wts[n * 16 + tid];
    }
    {
        float4 v = reinterpret_cast<const float4*>(X + (size_t)n * 1024)[tid];
        *reinterpret_cast<float4*>(xs + tid * 4) = v;
    }
    __syncthreads();
    #pragma unroll
    for (int q = 0; q < 4; ++q) {
        int e = wave * 4 + q;
        const float* row = UE + (size_t)sidx[e] * 1024;
        float acc = 0.f;
        #pragma unroll
        for (int c = 0; c < 4; ++c) {
            int h = c * 256 + lane * 4;
            float4 a = *reinterpret_cast<const float4*>(row + h);
            float4 xv = *reinterpret_cast<const float4*>(xs + h);
            acc += a.x * xv.x + a.y * xv.y + a.z * xv.z + a.w * xv.w;
        }
        acc = wave_sum(acc);
        if (lane == 0) {
            float s = acc / (1.f + __expf(-acc));   // silu
            ews[e] = s * swt[e];
        }
    }
    __syncthreads();
    float4 a = make_float4(0.f, 0.f, 0.f, 0.f);
    int h = tid * 4;
    #pragma unroll
    for (int e = 0; e < 16; ++e) {
        const float* row = DE + (size_t)sidx[e] * 1024;
        float4 v = *reinterpret_cast<const float4*>(row + h);
        float w = ews[e];
        a.x += w * v.x; a.y += w * v.y;
        a.z += w * v.z; a.w += w * v.w;
    }
    reinterpret_cast<float4*>(Out + (size_t)n * 1024)[tid] = a;
}

// ---------------- router stats / topk (proven) ----------------
__global__ void bn_stats(const float* __restrict__ R, float* __restrict__ stats) {
    int c = threadIdx.x;
    int r0 = blockIdx.x * 64;
    float s = 0.f, s2 = 0.f;
    for (int r = r0; r < r0 + 64; ++r) {
        float v = R[(size_t)r * 256 + c];
        s += v; s2 += v * v;
    }
    atomicAdd(&stats[c], s);
    atomicAdd(&stats[256 + c], s2);
}

__global__ __launch_bounds__(64) void router_topk(
    const float* __restrict__ R, const float* __restrict__ stats,
    int* __restrict__ idx_out, float* __restrict__ wt_out) {
    int n = blockIdx.x, lane = threadIdx.x;
    const float invN = 1.0f / 4096.0f;
    float z[4];
    #pragma unroll
    for (int p = 0; p < 4; ++p) {
        int c = p * 64 + lane;
        float mean = stats[c] * invN;
        float var = fmaxf(stats[256 + c] * invN - mean * mean, 0.f);  // biased var
        float v = R[(size_t)n * 256 + c];
        z[p] = (v - mean) * rsqrtf(var + 1e-5f);
    }
    float mx = wave_max(fmaxf(z[0], z[1]));
    float sx = __logf(wave_sum(__expf(z[0] - mx) + __expf(z[1] - mx)));
    float lx0 = z[0] - mx - sx, lx1 = z[1] - mx - sx;
    float my = wave_max(fmaxf(z[2], z[3]));
    float sy = __logf(wave_sum(__expf(z[2] - my) + __expf(z[3] - my)));
    float ly0 = z[2] - my - sy, ly1 = z[3] - my - sy;

    __shared__ float tx[16], ty[16];
    __shared__ int txc[16], tyc[16];
    float v0 = lx0, v1 = lx1;
    for (int t = 0; t < 16; ++t) {
        float bv; int bc;
        if (v1 > v0) { bv = v1; bc = lane + 64; } else { bv = v0; bc = lane; }
        wave_argmax(bv, bc);
        if (lane == 0) { tx[t] = bv; txc[t] = bc; }
        if (bc == lane) v0 = NEG_INF;
        else if (bc == lane + 64) v1 = NEG_INF;
    }
    v0 = ly0; v1 = ly1;
    for (int t = 0; t < 16; ++t) {
        float bv; int bc;
        if (v1 > v0) { bv = v1; bc = lane + 64; } else { bv = v0; bc = lane; }
        wave_argmax(bv, bc);
        if (lane == 0) { ty[t] = bv; tyc[t] = bc; }
        if (bc == lane) v0 = NEG_INF;
        else if (bc == lane + 64) v1 = NEG_INF;
    }
    __syncthreads();
    float cv[4]; int ci[4];
    #pragma unroll
    for (int p = 0; p < 4; ++p) {
        int pid = p * 64 + lane;
        cv[p] = tx[pid >> 4] + ty[pid & 15];
        ci[p] = pid;
    }
    for (int t = 0; t < 16; ++t) {
        float bv = cv[0]; int bc = ci[0];
        #pragma unroll
        for (int p = 1; p < 4; ++p)
            if (cv[p] > bv) { bv = cv[p]; bc = ci[p]; }
        wave_argmax(bv, bc);
        if (lane == 0) {
            idx_out[n * 16 + t] = txc[bc >> 4] * 128 + tyc[bc & 15];
            wt_out[n * 16 + t] = __expf(bv);
        }
        #pragma unroll
        for (int p = 0; p < 4; ++p)
            if (ci[p] == bc) cv[p] = NEG_INF;
    }
}

// ---------------- host ----------------
// Workspace: stats 16KB | idx 256KB | wt 256KB | union32 { R 4MB -> H2 32MB } = 34.1MB
// (known-safe from round 2). If ws_size >= 42.5MB, xb (8MB bf16 copy of x) is appended so
// gateup's A-tile uses global_load_lds (zero-VALU staging); else fp32-cvt fallback.
extern "C" void kernel_launch(void* const* d_in, const int* in_sizes, int n_in,
                              void* d_out, int out_size, void* d_ws, size_t ws_size,
                              hipStream_t stream) {
    const float* x   = (const float*)d_in[0];   // [4096,1024]
    const float* gw  = (const float*)d_in[1];   // [4096,1024]
    const float* uw  = (const float*)d_in[2];   // [4096,1024]
    const float* dw  = (const float*)d_in[3];   // [1024,4096]
    const float* rxw = (const float*)d_in[4];   // [128,1024]
    const float* ryw = (const float*)d_in[5];   // [128,1024]
    const float* ue  = (const float*)d_in[6];   // [16384,1024]
    const float* de  = (const float*)d_in[7];   // [16384,1024]
    float* out = (float*)d_out;                 // [4096,1024] fp32

    char* p = (char*)d_ws;
    float* stats = (float*)p; p += 16384;
    int*   idxb  = (int*)p;   p += 262144;
    float* wtb   = (float*)p; p += 262144;
    float* R     = (float*)p;                   // [4096,256] fp32, dead after router_topk
    u16*   H2    = (u16*)p;                     // aliases R: [4096,4096] bf16 (dense phase)

    bool useXb = ws_size >= 42483712ull;        // 34.1MB + 8MB
    u16* xb = (u16*)((char*)d_ws + 34095104ull);

    hipMemsetAsync(stats, 0, 512 * sizeof(float), stream);
    if (useXb) conv_x<<<4096, 256, 0, stream>>>(x, xb);

    gemm_router<<<dim3(4, 32), 256, 0, stream>>>(x, rxw, ryw, R);
    bn_stats<<<64, 256, 0, stream>>>(R, stats);
    router_topk<<<4096, 64, 0, stream>>>(R, stats, idxb, wtb);
    expert_store<<<4096, 256, 0, stream>>>(x, ue, de, idxb, wtb, out);   // experts -> out

    if (useXb) gemm_gateup<true ><<<1024, 256, 0, stream>>>(nullptr, xb, gw, uw, H2);
    else       gemm_gateup<false><<<1024, 256, 0, stream>>>(x, nullptr, gw, uw, H2);
    gemm_down_add<<<512, 256, 0, stream>>>(H2, dw, out);
}

// Round 4
// 515.927 us; speedup vs baseline: 1.1761x; 1.0584x over previous
//
#include <hip/hip_runtime.h>

typedef float f32x4 __attribute__((ext_vector_type(4)));
typedef short bf16x8 __attribute__((ext_vector_type(8)));
typedef unsigned short u16;

#define NEG_INF (-1e30f)

__device__ __forceinline__ u16 f2bf(float f) {
    unsigned u = __builtin_bit_cast(unsigned, f);
    unsigned r = u + 0x7FFFu + ((u >> 16) & 1u);  // RNE
    return (u16)(r >> 16);
}
// 2x f32 -> packed bf16 in one VALU op (RNE, identical to f2bf; validated round 2).
__device__ __forceinline__ unsigned pk2(float a, float b) {
    unsigned r;
    asm("v_cvt_pk_bf16_f32 %0, %1, %2" : "=v"(r) : "v"(a), "v"(b));
    return r;
}

__device__ __forceinline__ float wave_max(float v) {
    #pragma unroll
    for (int o = 32; o > 0; o >>= 1) v = fmaxf(v, __shfl_xor(v, o, 64));
    return v;
}
__device__ __forceinline__ float wave_sum(float v) {
    #pragma unroll
    for (int o = 32; o > 0; o >>= 1) v += __shfl_xor(v, o, 64);
    return v;
}
__device__ __forceinline__ void wave_argmax(float& v, int& i) {
    #pragma unroll
    for (int o = 32; o > 0; o >>= 1) {
        float ov = __shfl_xor(v, o, 64);
        int oi = __shfl_xor(i, o, 64);
        if (ov > v || (ov == v && oi < i)) { v = ov; i = oi; }
    }
}

// ---------------- staging / swizzle ----------------
// Async global->LDS 16B. LDS dest is wave-uniform base + lane*16 in all uses below.
__device__ __forceinline__ void g2l16(const void* g, void* l) {
    __builtin_amdgcn_global_load_lds((__attribute__((address_space(1))) void*)g,
                                     (__attribute__((address_space(3))) void*)l,
                                     16, 0, 0);
}
// Bank-conflict swizzles on 16B chunk index (rule #21: LDS linear; swizzle applied to
// global SOURCE for g2l16 paths, to ds_write addr for reg-staged paths, and to all reads).
__device__ __forceinline__ int swz8(int row, int c) { return c ^ (row & 7); }         // [*][64] tiles
__device__ __forceinline__ int swz4(int row, int c) { return c ^ ((row >> 1) & 3); }  // [*][32] tiles

// [ROWS][64] bf16 tile staged via global_load_lds, source pre-swizzled. 2 rounds.
template<int NTHR>
__device__ __forceinline__ void stageA64(const u16* __restrict__ src, int ld,
                                         u16* dst, int tid) {
    #pragma unroll
    for (int r = 0; r < 2; ++r) {
        int e = r * NTHR * 8 + tid * 8;
        int row = e >> 6, c = (e >> 3) & 7;
        g2l16(src + (size_t)row * ld + swz8(row, c) * 8, dst + e);
    }
}
// [128][32] bf16 tile (256 thr), source pre-swizzled. 2 rounds.
__device__ __forceinline__ void stageA32(const u16* __restrict__ src, int ld,
                                         u16* dst, int tid) {
    #pragma unroll
    for (int r = 0; r < 2; ++r) {
        int e = r * 2048 + tid * 8;
        int row = e >> 5, c = (e >> 3) & 3;
        g2l16(src + (size_t)row * ld + swz4(row, c) * 8, dst + e);
    }
}

// fp32 tile load->regs / cvt+write->LDS (issue-early / write-late split, T14).
// [64][64], 256 thr: 16 floats/thread.
__device__ __forceinline__ void loadT64_256(const float* __restrict__ src, int ld,
                                            int tid, float4* v) {
    int row = tid >> 2, col = (tid & 3) * 16;
    const float* s = src + (size_t)row * ld + col;
    v[0] = *reinterpret_cast<const float4*>(s);
    v[1] = *reinterpret_cast<const float4*>(s + 4);
    v[2] = *reinterpret_cast<const float4*>(s + 8);
    v[3] = *reinterpret_cast<const float4*>(s + 12);
}
__device__ __forceinline__ void writeT64_256(const float4* v, u16* dst, int tid) {
    int row = tid >> 2, c0 = (tid & 3) * 2;
    uint4 p0 = { pk2(v[0].x, v[0].y), pk2(v[0].z, v[0].w), pk2(v[1].x, v[1].y), pk2(v[1].z, v[1].w) };
    uint4 p1 = { pk2(v[2].x, v[2].y), pk2(v[2].z, v[2].w), pk2(v[3].x, v[3].y), pk2(v[3].z, v[3].w) };
    *reinterpret_cast<uint4*>(dst + row * 64 + swz8(row, c0) * 8) = p0;
    *reinterpret_cast<uint4*>(dst + row * 64 + swz8(row, c0 + 1) * 8) = p1;
}
// [64][64], 512 thr: 8 floats/thread.
__device__ __forceinline__ void loadT64_512(const float* __restrict__ src, int ld,
                                            int tid, float4* v) {
    int row = tid >> 3, col = (tid & 7) * 8;
    const float* s = src + (size_t)row * ld + col;
    v[0] = *reinterpret_cast<const float4*>(s);
    v[1] = *reinterpret_cast<const float4*>(s + 4);
}
__device__ __forceinline__ void writeT64_512(const float4* v, u16* dst, int tid) {
    int row = tid >> 3, c = tid & 7;
    uint4 p = { pk2(v[0].x, v[0].y), pk2(v[0].z, v[0].w), pk2(v[1].x, v[1].y), pk2(v[1].z, v[1].w) };
    *reinterpret_cast<uint4*>(dst + row * 64 + swz8(row, c) * 8) = p;
}
// [128][32], 256 thr: 16 floats/thread.
__device__ __forceinline__ void loadT32(const float* __restrict__ src, int ld,
                                        int tid, float4* v) {
    int row = tid >> 1, col = (tid & 1) * 16;
    const float* s = src + (size_t)row * ld + col;
    v[0] = *reinterpret_cast<const float4*>(s);
    v[1] = *reinterpret_cast<const float4*>(s + 4);
    v[2] = *reinterpret_cast<const float4*>(s + 8);
    v[3] = *reinterpret_cast<const float4*>(s + 12);
}
__device__ __forceinline__ void writeT32(const float4* v, u16* dst, int tid) {
    int row = tid >> 1, c0 = (tid & 1) * 2;
    uint4 p0 = { pk2(v[0].x, v[0].y), pk2(v[0].z, v[0].w), pk2(v[1].x, v[1].y), pk2(v[1].z, v[1].w) };
    uint4 p1 = { pk2(v[2].x, v[2].y), pk2(v[2].z, v[2].w), pk2(v[3].x, v[3].y), pk2(v[3].z, v[3].w) };
    *reinterpret_cast<uint4*>(dst + row * 32 + swz4(row, c0) * 8) = p0;
    *reinterpret_cast<uint4*>(dst + row * 32 + swz4(row, c0 + 1) * 8) = p1;
}

// Swizzled frag reads. mfma_f32_16x16x32_bf16: lane holds [m|n=lane&15][k=ks*32+(lane>>4)*8..+7]
__device__ __forceinline__ bf16x8 frag64s(const u16* lds, int row0, int ks, int lane) {
    int row = row0 + (lane & 15);
    int c = ks * 4 + (lane >> 4);
    return *reinterpret_cast<const bf16x8*>(lds + row * 64 + swz8(row, c) * 8);
}
__device__ __forceinline__ bf16x8 frag32s(const u16* lds, int row0, int lane) {
    int row = row0 + (lane & 15);
    int c = lane >> 4;
    return *reinterpret_cast<const bf16x8*>(lds + row * 32 + swz4(row, c) * 8);
}

// ---------------- x -> bf16 (one-time; x is contiguous [4096][1024]) ----------------
__global__ void conv_x(const float* __restrict__ s, u16* __restrict__ d) {
    size_t i = (size_t)blockIdx.x * 256 + threadIdx.x;   // float4 index
    float4 v = *reinterpret_cast<const float4*>(s + i * 4);
    uint2 pk;
    pk.x = pk2(v.x, v.y); pk.y = pk2(v.z, v.w);
    *reinterpret_cast<uint2*>(d + i * 4) = pk;
}

// ---------------- router GEMM: R[4096,256] = x @ [rxw;ryw]^T ----------------
// 64x64 tile, BK=64, 4 waves (2x2 of 32x32), dbuf 2-phase, grid (4,64)=256 blocks.
template<bool ABF>
__global__ __launch_bounds__(256, 2) void gemm_router(
    const float* __restrict__ Xf, const u16* __restrict__ Xb,
    const float* __restrict__ RX, const float* __restrict__ RY,
    float* __restrict__ R) {
    __shared__ __align__(16) u16 As[2][4096];
    __shared__ __align__(16) u16 Bs[2][4096];
    int tid = threadIdx.x, lane = tid & 63, wave = tid >> 6;
    int rowBase = blockIdx.y * 64, colBase = blockIdx.x * 64;
    const float* Bp = (blockIdx.x < 2) ? RX + (size_t)colBase * 1024
                                       : RY + (size_t)(colBase - 128) * 1024;
    int wm = (wave >> 1) * 32, wn = (wave & 1) * 32;
    f32x4 acc[2][2] = {};
    float4 av[4], bv[4];
    if constexpr (ABF) stageA64<256>(Xb + (size_t)rowBase * 1024, 1024, As[0], tid);
    else               { loadT64_256(Xf + (size_t)rowBase * 1024, 1024, tid, av);
                         writeT64_256(av, As[0], tid); }
    loadT64_256(Bp, 1024, tid, bv);
    writeT64_256(bv, Bs[0], tid);
    __syncthreads();
    int cur = 0;
    for (int t = 0; t < 16; ++t) {
        if (t < 15) {  // issue next tile BEFORE compute (latency hides under MFMA)
            int k0 = (t + 1) * 64;
            if constexpr (ABF) stageA64<256>(Xb + (size_t)rowBase * 1024 + k0, 1024, As[cur ^ 1], tid);
            else               loadT64_256(Xf + (size_t)rowBase * 1024 + k0, 1024, tid, av);
            loadT64_256(Bp + k0, 1024, tid, bv);
        }
        #pragma unroll
        for (int ks = 0; ks < 2; ++ks) {
            bf16x8 af[2], bfr[2];
            #pragma unroll
            for (int i = 0; i < 2; ++i) af[i] = frag64s(As[cur], wm + i * 16, ks, lane);
            #pragma unroll
            for (int j = 0; j < 2; ++j) bfr[j] = frag64s(Bs[cur], wn + j * 16, ks, lane);
            #pragma unroll
            for (int i = 0; i < 2; ++i)
                #pragma unroll
                for (int j = 0; j < 2; ++j)
                    acc[i][j] = __builtin_amdgcn_mfma_f32_16x16x32_bf16(af[i], bfr[j], acc[i][j], 0, 0, 0);
        }
        if (t < 15) {
            if constexpr (!ABF) writeT64_256(av, As[cur ^ 1], tid);
            writeT64_256(bv, Bs[cur ^ 1], tid);
        }
        __syncthreads();   // single barrier/iter: drains next-tile stores + orders buffers
        cur ^= 1;
    }
    int rq = (lane >> 4) * 4, cq = lane & 15;
    #pragma unroll
    for (int i = 0; i < 2; ++i)
        #pragma unroll
        for (int j = 0; j < 2; ++j) {
            int col = colBase + wn + j * 16 + cq;
            #pragma unroll
            for (int r = 0; r < 4; ++r) {
                int row = rowBase + wm + i * 16 + rq + r;
                R[(size_t)row * 256 + col] = acc[i][j][r];
            }
        }
}

// ---------------- gateup: 128x128 tile, BK=32, dbuf 2-phase, 4 waves 2x2 of 64x64 -------
// H2 = silu(x Gt) * (x Ut), bf16. Grid 1024, XCD decode (xb row-panel L2-resident).
template<bool ABF>
__global__ __launch_bounds__(256, 2) void gemm_gateup(
    const float* __restrict__ Xf, const u16* __restrict__ Xb,
    const float* __restrict__ GW, const float* __restrict__ UW,
    u16* __restrict__ H2) {
    __shared__ __align__(16) u16 As[2][4096];
    __shared__ __align__(16) u16 Gs[2][4096];
    __shared__ __align__(16) u16 Us[2][4096];
    int tid = threadIdx.x, lane = tid & 63, wave = tid >> 6;
    int b = blockIdx.x, xcd = b & 7, ii = b >> 3;
    int by = xcd * 4 + (ii >> 5), bx = ii & 31;
    int rowBase = by * 128, colBase = bx * 128;
    const float* Gp = GW + (size_t)colBase * 1024;
    const float* Up = UW + (size_t)colBase * 1024;
    int wm = (wave >> 1) * 64, wn = (wave & 1) * 64;
    f32x4 accg[4][4] = {}, accu[4][4] = {};
    float4 av[4], gv[4], uv[4];
    if constexpr (ABF) stageA32(Xb + (size_t)rowBase * 1024, 1024, As[0], tid);
    else               { loadT32(Xf + (size_t)rowBase * 1024, 1024, tid, av);
                         writeT32(av, As[0], tid); }
    loadT32(Gp, 1024, tid, gv);
    loadT32(Up, 1024, tid, uv);
    writeT32(gv, Gs[0], tid);
    writeT32(uv, Us[0], tid);
    __syncthreads();
    int cur = 0;
    for (int t = 0; t < 32; ++t) {
        if (t < 31) {
            int k0 = (t + 1) * 32;
            if constexpr (ABF) stageA32(Xb + (size_t)rowBase * 1024 + k0, 1024, As[cur ^ 1], tid);
            else               loadT32(Xf + (size_t)rowBase * 1024 + k0, 1024, tid, av);
            loadT32(Gp + k0, 1024, tid, gv);
            loadT32(Up + k0, 1024, tid, uv);
        }
        bf16x8 gf[4], uf[4];
        #pragma unroll
        for (int j = 0; j < 4; ++j) { gf[j] = frag32s(Gs[cur], wn + j * 16, lane);
                                      uf[j] = frag32s(Us[cur], wn + j * 16, lane); }
        #pragma unroll
        for (int i = 0; i < 4; ++i) {
            bf16x8 af = frag32s(As[cur], wm + i * 16, lane);
            #pragma unroll
            for (int j = 0; j < 4; ++j) {
                accg[i][j] = __builtin_amdgcn_mfma_f32_16x16x32_bf16(af, gf[j], accg[i][j], 0, 0, 0);
                accu[i][j] = __builtin_amdgcn_mfma_f32_16x16x32_bf16(af, uf[j], accu[i][j], 0, 0, 0);
            }
        }
        if (t < 31) {
            if constexpr (!ABF) writeT32(av, As[cur ^ 1], tid);
            writeT32(gv, Gs[cur ^ 1], tid);
            writeT32(uv, Us[cur ^ 1], tid);
        }
        __syncthreads();
        cur ^= 1;
    }
    int rq = (lane >> 4) * 4, cq = lane & 15;
    #pragma unroll
    for (int i = 0; i < 4; ++i)
        #pragma unroll
        for (int j = 0; j < 4; ++j) {
            int col = colBase + wn + j * 16 + cq;
            #pragma unroll
            for (int r = 0; r < 4; ++r) {
                int row = rowBase + wm + i * 16 + rq + r;
                float gvv = accg[i][j][r], uvv = accu[i][j][r];
                float h = (gvv / (1.f + __expf(-gvv))) * uvv;   // silu(g)*u
                H2[(size_t)row * 4096 + col] = f2bf(h);
            }
        }
}

// ---------------- down: Out += H2 @ dw^T. 128x64 tile, BK=64, 512 thr (8 waves 4x2
// of 32x32), dbuf 2-phase, grid 512 (2 blk/CU -> 16 waves/CU), XCD decode. -------------
__global__ __launch_bounds__(512, 4) void gemm_down_pipe(
    const u16* __restrict__ H2, const float* __restrict__ DW, float* __restrict__ Out) {
    __shared__ __align__(16) u16 As[2][8192];   // 2 x 128x64
    __shared__ __align__(16) u16 Bs[2][4096];   // 2 x  64x64
    int tid = threadIdx.x, lane = tid & 63, wave = tid >> 6;
    int b = blockIdx.x, xcd = b & 7, ii = b >> 3;
    int by = xcd * 4 + (ii >> 4), bx = ii & 15;
    int rowBase = by * 128, colBase = bx * 64;
    const u16* Ap = H2 + (size_t)rowBase * 4096;
    const float* Bp = DW + (size_t)colBase * 4096;
    int wm = (wave >> 1) * 32, wn = (wave & 1) * 32;
    f32x4 acc[2][2] = {};
    float4 bv[2];
    stageA64<512>(Ap, 4096, As[0], tid);
    loadT64_512(Bp, 4096, tid, bv);
    writeT64_512(bv, Bs[0], tid);
    __syncthreads();
    int cur = 0;
    for (int t = 0; t < 64; ++t) {
        if (t < 63) {
            int k0 = (t + 1) * 64;
            stageA64<512>(Ap + k0, 4096, As[cur ^ 1], tid);
            loadT64_512(Bp + k0, 4096, tid, bv);
        }
        #pragma unroll
        for (int ks = 0; ks < 2; ++ks) {
            bf16x8 af[2], bfr[2];
            #pragma unroll
            for (int i = 0; i < 2; ++i) af[i] = frag64s(As[cur], wm + i * 16, ks, lane);
            #pragma unroll
            for (int j = 0; j < 2; ++j) bfr[j] = frag64s(Bs[cur], wn + j * 16, ks, lane);
            #pragma unroll
            for (int i = 0; i < 2; ++i)
                #pragma unroll
                for (int j = 0; j < 2; ++j)
                    acc[i][j] = __builtin_amdgcn_mfma_f32_16x16x32_bf16(af[i], bfr[j], acc[i][j], 0, 0, 0);
        }
        if (t < 63) writeT64_512(bv, Bs[cur ^ 1], tid);
        __syncthreads();
        cur ^= 1;
    }
    int rq = (lane >> 4) * 4, cq = lane & 15;
    #pragma unroll
    for (int i = 0; i < 2; ++i)
        #pragma unroll
        for (int j = 0; j < 2; ++j) {
            int col = colBase + wn + j * 16 + cq;
            #pragma unroll
            for (int r = 0; r < 4; ++r) {
                int row = rowBase + wm + i * 16 + rq + r;
                size_t o = (size_t)row * 1024 + col;
                Out[o] = acc[i][j][r] + Out[o];   // add experts term (same-thread RMW)
            }
        }
}

// ---------------- expert combine (round-1 exact: 4.6KB LDS, high occupancy) -------------
__global__ __launch_bounds__(256) void expert_store(
    const float* __restrict__ X, const float* __restrict__ UE, const float* __restrict__ DE,
    const int* __restrict__ idxs, const float* __restrict__ wts, float* __restrict__ Out) {
    int n = blockIdx.x, tid = threadIdx.x;
    int lane = tid & 63, wave = tid >> 6;
    __shared__ float xs[1024];
    __shared__ float ews[16];
    __shared__ int sidx[16];
    __shared__ float swt[16];
    if (tid < 16) {
        sidx[tid] = min(max(idxs[n * 16 + tid], 0), 16383);  // clamp: no wild gathers
        swt[tid] = wts[n * 16 + tid];
    }
    {
        float4 v = reinterpret_cast<const float4*>(X + (size_t)n * 1024)[tid];
        *reinterpret_cast<float4*>(xs + tid * 4) = v;
    }
    __syncthreads();
    #pragma unroll
    for (int q = 0; q < 4; ++q) {
        int e = wave * 4 + q;
        const float* row = UE + (size_t)sidx[e] * 1024;
        float acc = 0.f;
        #pragma unroll
        for (int c = 0; c < 4; ++c) {
            int h = c * 256 + lane * 4;
            float4 a = *reinterpret_cast<const float4*>(row + h);
            float4 xv = *reinterpret_cast<const float4*>(xs + h);
            acc += a.x * xv.x + a.y * xv.y + a.z * xv.z + a.w * xv.w;
        }
        acc = wave_sum(acc);
        if (lane == 0) {
            float s = acc / (1.f + __expf(-acc));   // silu
            ews[e] = s * swt[e];
        }
    }
    __syncthreads();
    float4 a = make_float4(0.f, 0.f, 0.f, 0.f);
    int h = tid * 4;
    #pragma unroll
    for (int e = 0; e < 16; ++e) {
        const float* row = DE + (size_t)sidx[e] * 1024;
        float4 v = *reinterpret_cast<const float4*>(row + h);
        float w = ews[e];
        a.x += w * v.x; a.y += w * v.y;
        a.z += w * v.z; a.w += w * v.w;
    }
    reinterpret_cast<float4*>(Out + (size_t)n * 1024)[tid] = a;
}

// ---------------- router stats / topk (proven) ----------------
__global__ void bn_stats(const float* __restrict__ R, float* __restrict__ stats) {
    int c = threadIdx.x;
    int r0 = blockIdx.x * 64;
    float s = 0.f, s2 = 0.f;
    for (int r = r0; r < r0 + 64; ++r) {
        float v = R[(size_t)r * 256 + c];
        s += v; s2 += v * v;
    }
    atomicAdd(&stats[c], s);
    atomicAdd(&stats[256 + c], s2);
}

__global__ __launch_bounds__(64) void router_topk(
    const float* __restrict__ R, const float* __restrict__ stats,
    int* __restrict__ idx_out, float* __restrict__ wt_out) {
    int n = blockIdx.x, lane = threadIdx.x;
    const float invN = 1.0f / 4096.0f;
    float z[4];
    #pragma unroll
    for (int p = 0; p < 4; ++p) {
        int c = p * 64 + lane;
        float mean = stats[c] * invN;
        float var = fmaxf(stats[256 + c] * invN - mean * mean, 0.f);  // biased var
        float v = R[(size_t)n * 256 + c];
        z[p] = (v - mean) * rsqrtf(var + 1e-5f);
    }
    float mx = wave_max(fmaxf(z[0], z[1]));
    float sx = __logf(wave_sum(__expf(z[0] - mx) + __expf(z[1] - mx)));
    float lx0 = z[0] - mx - sx, lx1 = z[1] - mx - sx;
    float my = wave_max(fmaxf(z[2], z[3]));
    float sy = __logf(wave_sum(__expf(z[2] - my) + __expf(z[3] - my)));
    float ly0 = z[2] - my - sy, ly1 = z[3] - my - sy;

    __shared__ float tx[16], ty[16];
    __shared__ int txc[16], tyc[16];
    float v0 = lx0, v1 = lx1;
    for (int t = 0; t < 16; ++t) {
        float bv; int bc;
        if (v1 > v0) { bv = v1; bc = lane + 64; } else { bv = v0; bc = lane; }
        wave_argmax(bv, bc);
        if (lane == 0) { tx[t] = bv; txc[t] = bc; }
        if (bc == lane) v0 = NEG_INF;
        else if (bc == lane + 64) v1 = NEG_INF;
    }
    v0 = ly0; v1 = ly1;
    for (int t = 0; t < 16; ++t) {
        float bv; int bc;
        if (v1 > v0) { bv = v1; bc = lane + 64; } else { bv = v0; bc = lane; }
        wave_argmax(bv, bc);
        if (lane == 0) { ty[t] = bv; tyc[t] = bc; }
        if (bc == lane) v0 = NEG_INF;
        else if (bc == lane + 64) v1 = NEG_INF;
    }
    __syncthreads();
    float cv[4]; int ci[4];
    #pragma unroll
    for (int p = 0; p < 4; ++p) {
        int pid = p * 64 + lane;
        cv[p] = tx[pid >> 4] + ty[pid & 15];
        ci[p] = pid;
    }
    for (int t = 0; t < 16; ++t) {
        float bv = cv[0]; int bc = ci[0];
        #pragma unroll
        for (int p = 1; p < 4; ++p)
            if (cv[p] > bv) { bv = cv[p]; bc = ci[p]; }
        wave_argmax(bv, bc);
        if (lane == 0) {
            idx_out[n * 16 + t] = txc[bc >> 4] * 128 + tyc[bc & 15];
            wt_out[n * 16 + t] = __expf(bv);
        }
        #pragma unroll
        for (int p = 0; p < 4; ++p)
            if (ci[p] == bc) cv[p] = NEG_INF;
    }
}

// ---------------- host ----------------
// Workspace: stats 16KB | idx 256KB | wt 256KB | union32 { R 4MB -> H2 32MB } = 34.1MB
// (known-safe). If ws_size >= 42.5MB, xb (8MB bf16 copy of x) appended: A-tiles of router
// and gateup then use global_load_lds (zero-VALU staging); else fp32-cvt reg fallback.
extern "C" void kernel_launch(void* const* d_in, const int* in_sizes, int n_in,
                              void* d_out, int out_size, void* d_ws, size_t ws_size,
                              hipStream_t stream) {
    const float* x   = (const float*)d_in[0];   // [4096,1024]
    const float* gw  = (const float*)d_in[1];   // [4096,1024]
    const float* uw  = (const float*)d_in[2];   // [4096,1024]
    const float* dw  = (const float*)d_in[3];   // [1024,4096]
    const float* rxw = (const float*)d_in[4];   // [128,1024]
    const float* ryw = (const float*)d_in[5];   // [128,1024]
    const float* ue  = (const float*)d_in[6];   // [16384,1024]
    const float* de  = (const float*)d_in[7];   // [16384,1024]
    float* out = (float*)d_out;                 // [4096,1024] fp32

    char* p = (char*)d_ws;
    float* stats = (float*)p; p += 16384;
    int*   idxb  = (int*)p;   p += 262144;
    float* wtb   = (float*)p; p += 262144;
    float* R     = (float*)p;                   // [4096,256] fp32, dead after router_topk
    u16*   H2    = (u16*)p;                     // aliases R: [4096,4096] bf16 (dense phase)

    bool useXb = ws_size >= 42483712ull;        // 34.1MB + 8MB
    u16* xb = (u16*)((char*)d_ws + 34095104ull);

    hipMemsetAsync(stats, 0, 512 * sizeof(float), stream);
    if (useXb) conv_x<<<4096, 256, 0, stream>>>(x, xb);

    if (useXb) gemm_router<true ><<<dim3(4, 64), 256, 0, stream>>>(x, xb, rxw, ryw, R);
    else       gemm_router<false><<<dim3(4, 64), 256, 0, stream>>>(x, (const u16*)x, rxw, ryw, R);
    bn_stats<<<64, 256, 0, stream>>>(R, stats);
    router_topk<<<4096, 64, 0, stream>>>(R, stats, idxb, wtb);
    expert_store<<<4096, 256, 0, stream>>>(x, ue, de, idxb, wtb, out);   // experts -> out

    if (useXb) gemm_gateup<true ><<<1024, 256, 0, stream>>>(x, xb, gw, uw, H2);
    else       gemm_gateup<false><<<1024, 256, 0, stream>>>(x, (const u16*)x, gw, uw, H2);
    gemm_down_pipe<<<512, 512, 0, stream>>>(H2, dw, out);
}